// Round 13
// baseline (429.463 us; speedup 1.0000x reference)
//
#include <hip/hip_runtime.h>
#include <math.h>

// NNFM loss on MI355X.
// loss = mean_i (1 - max_j (xhat_i . shat_j)),  xhat/shat = column-normalized feats.
// R2: XOR-swizzle -> 0 conflicts. R5: fp8 BK=128. R7: i8 16x16x64.
// R8: 2 blocks/CU overlap -> 239us. R10: XCD L2-residency map -> GEMM 180us.
// R11: A direct from L2, launch_bounds(256,4) -> 64 VGPR cap -> spill (layout OK).
// R12: A direct at (256,2): correct but A L2-latency (~200-400cyc) sits in the
//      barrier-locked phase wait -> 270us, MfmaUtil 33%.
// R13: one-phase A register prefetch (aEv/aOd named sets, unroll-by-2; A depends
//      only on kk). Phase wait vmcnt(12): drains A(t) (issued last phase) + B(t+1),
//      keeps A(t+1)+B(t+2) in flight. A latency hidden under a full MFMA phase.

#define C_DIM 768
#define P_DIM 16384
#define KT 6            // K-tiles (BK=128) : 768/128
#define NJT 32          // j-tiles per block: 4096/128
#define JSPLIT 4
#define EPSF 1e-8f
#define QSCALE 256.0f

typedef unsigned char u8;
typedef int i32x4 __attribute__((ext_vector_type(4)));

// workspace layout (bytes)
#define OFF_XN   0
#define OFF_SN   25165824UL
#define OFF_INVX 50331648UL
#define OFF_INVS 50397184UL
#define OFF_MAX  50462720UL                 // 4 * 16384 * 4

__device__ __forceinline__ void async_copy16(const void* gsrc, void* ldst) {
    __builtin_amdgcn_global_load_lds(
        (const __attribute__((address_space(1))) void*)gsrc,
        (__attribute__((address_space(3))) void*)ldst,
        16, 0, 0);
}

#define CFENCE() asm volatile("" ::: "memory")
#define BARRIER() { CFENCE(); __builtin_amdgcn_s_barrier(); CFENCE(); }

// --- 1. column L2 norms: inv = QSCALE/(||col|| + eps); one thread per column ---
__global__ void norm_kernel(const float* __restrict__ x, const float* __restrict__ s,
                            float* __restrict__ invx, float* __restrict__ invs) {
    const float* src = blockIdx.y == 0 ? x : s;
    float* dst = (blockIdx.y == 0) ? invx : invs;
    int j = blockIdx.x * 256 + threadIdx.x;        // 0..16383
    float sum = 0.f;
    for (int c = 0; c < C_DIM; ++c) {
        float v = src[(size_t)c * P_DIM + j];
        sum += v * v;
    }
    dst[j] = QSCALE / (sqrtf(sum) + EPSF);
}

// --- 2. transpose, normalize*256, round to int8 ---
// Sn (z=1): row-major [p][c] (DMA->LDS path).
// Xn (z=0): fragment-linear for direct global->VGPR MFMA A-operands:
//   byte addr = (((kt*1024 + g)*2 + ks)<<10) + lane*16 + (kb&15),
//   g = row>>4, lane = (kb>>4)*16 + (row&15). Verified (R11/R12 absmax 0.0).
__global__ void tnorm_kernel(const float* __restrict__ x, const float* __restrict__ s,
                             const float* __restrict__ invx, const float* __restrict__ invs,
                             u8* __restrict__ Xn, u8* __restrict__ Sn) {
    __shared__ float tile[64][65];
    const float* src = blockIdx.z ? s : x;
    const float* inv = blockIdx.z ? invs : invx;
    u8* dst = blockIdx.z ? Sn : Xn;
    int c0 = blockIdx.y * 64;
    int j0 = blockIdx.x * 64;
    int t = threadIdx.x;
    #pragma unroll
    for (int it = 0; it < 16; ++it) {
        int idx = it * 256 + t;
        int cr = idx >> 6, jc = idx & 63;
        tile[cr][jc] = src[(c0 + cr) * P_DIM + j0 + jc];
    }
    __syncthreads();
    const int kt = c0 >> 7;
    const int ks = (c0 >> 6) & 1;
    #pragma unroll
    for (int it = 0; it < 2; ++it) {
        int item = it * 256 + t;
        int jr = item >> 3;
        int oct = item & 7;
        float iv = inv[j0 + jr];
        unsigned long long pk = 0;
        #pragma unroll
        for (int o = 0; o < 8; ++o) {
            float v = tile[oct * 8 + o][jr] * iv;
            v = fminf(fmaxf(v, -127.0f), 127.0f);
            int q = (int)rintf(v);
            pk |= ((unsigned long long)(unsigned)(q & 0xFF)) << (8 * o);
        }
        size_t addr;
        if (blockIdx.z) {
            addr = (size_t)(j0 + jr) * C_DIM + c0 + oct * 8;
        } else {
            const int g = (j0 + jr) >> 4;
            const int lane = ((oct >> 1) << 4) + (jr & 15);
            addr = ((((size_t)kt * 1024 + g) * 2 + ks) << 10) + lane * 16 + ((oct & 1) << 3);
        }
        *(unsigned long long*)(dst + addr) = pk;
    }
}

// --- 3. 128x128-tile i8 GEMM: A prefetched global->VGPR, B via LDS; 2 blocks/CU ---
__global__ __launch_bounds__(256, 2) void nnfm_gemm_max(
    const u8* __restrict__ Xn, const u8* __restrict__ Sn,
    float* __restrict__ wmax) {
    __shared__ __align__(16) u8 smB[2][128 * 128];

    const int bid = blockIdx.x;
    const int xcd = bid & 7;
    const int idx = bid >> 3;               // 0..63
    const int iblk = xcd * 16 + (idx & 15);
    const int split = idx >> 4;             // 0..3
    const int i0 = iblk * 128;
    const int jbase = split * (P_DIM / JSPLIT);

    const int tid = threadIdx.x;
    const int lane = tid & 63;
    const int wid = tid >> 6;
    const int wrow = (wid >> 1) * 64;
    const int wcol = (wid & 1) * 64;
    const int lm = lane & 15;

    const int srow = wid * 8 + (lane >> 3);                // staging row (+c*32)
    const int scol = ((lane & 7) ^ (lane >> 3)) * 16;      // swizzled source col
    const int kidx0 = (((lane >> 4) + 0) ^ (lane & 7)) * 16;
    const int kidx1 = (((lane >> 4) + 4) ^ (lane & 7)) * 16;

    // A fragment base: g = iblk*8 + wrow/16 + m ; addr = ((kt*1024+g)*2+ks)<<10 + lane*16
    const u8* Abase = Xn + ((((size_t)iblk * 8 + (wrow >> 4)) * 2) << 10) + lane * 16;

#define STAGE_B(jt_t, kk_t, buf_t) { \
    _Pragma("unroll") \
    for (int c = 0; c < 4; ++c) \
      async_copy16(Sn + (size_t)(jbase + (jt_t) * 128 + c * 32 + srow) * C_DIM + (kk_t) * 128 + scol, \
                   &smB[buf_t][(c * 32 + wid * 8) * 128]); }

#define RD_B(BUF) { \
    _Pragma("unroll") \
    for (int n = 0; n < 4; ++n) { \
      bF[n][0] = *(const i32x4*)&smB[BUF][(wcol + n * 16 + lm) * 128 + kidx0]; \
      bF[n][1] = *(const i32x4*)&smB[BUF][(wcol + n * 16 + lm) * 128 + kidx1]; \
    } }

#define LD_A(SET, kt_t) { \
    _Pragma("unroll") \
    for (int m = 0; m < 4; ++m) { \
      SET[m][0] = *(const i32x4*)(Abase + ((((size_t)(kt_t) * 1024 + m) * 2 + 0) << 10)); \
      SET[m][1] = *(const i32x4*)(Abase + ((((size_t)(kt_t) * 1024 + m) * 2 + 1) << 10)); \
    } }

#define MFMA32(ASET, DOZERO) { \
    if (DOZERO) { \
      _Pragma("unroll") \
      for (int m = 0; m < 4; ++m) \
        _Pragma("unroll") \
        for (int n = 0; n < 4; ++n) \
          acc[m][n] = i32x4{0, 0, 0, 0}; \
    } \
    __builtin_amdgcn_s_setprio(1); \
    _Pragma("unroll") \
    for (int ks = 0; ks < 2; ++ks) \
      _Pragma("unroll") \
      for (int m = 0; m < 4; ++m) \
        _Pragma("unroll") \
        for (int n = 0; n < 4; ++n) \
          acc[m][n] = __builtin_amdgcn_mfma_i32_16x16x64_i8(ASET[m][ks], bF[n][ks], acc[m][n], 0, 0, 0); \
    __builtin_amdgcn_s_setprio(0); }

#define FOLD_RMAX() { \
    _Pragma("unroll") \
    for (int m = 0; m < 4; ++m) \
      _Pragma("unroll") \
      for (int r = 0; r < 4; ++r) { \
        int mx = acc[m][0][r]; \
        _Pragma("unroll") \
        for (int n = 1; n < 4; ++n) \
          if (acc[m][n][r] > mx) mx = acc[m][n][r]; \
        if (mx > rmax[m][r]) rmax[m][r] = mx; \
      } }

    i32x4 acc[4][4];
    int rmax[4][4];
    i32x4 aEv[4][2], aOd[4][2], bF[4][2];
    #pragma unroll
    for (int m = 0; m < 4; ++m)
        #pragma unroll
        for (int r = 0; r < 4; ++r) rmax[m][r] = (int)0x80000000;

    // prologue: B(0)->buf0, B(1)->buf1 (8 DMA), A(0)->aEv (8 loads); drain all once.
    STAGE_B(0, 0, 0);
    STAGE_B(0, 1, 1);
    LD_A(aEv, 0)
    asm volatile("s_waitcnt vmcnt(0)" ::: "memory");
    BARRIER();

    for (int jt = 0; jt < NJT; ++jt) {
        #pragma unroll
        for (int kp = 0; kp < 3; ++kp) {
            const int kk = kp * 2;           // even phase: use aEv, load aOd
            {
                const int buf = 0;           // kk even -> buf 0
                int kk2 = kk + 2, jt2 = jt;
                if (kk2 >= KT) { kk2 -= KT; jt2 = (jt + 1) & (NJT - 1); }
                RD_B(buf)
                LD_A(aOd, kk + 1)
                STAGE_B(jt2, kk2, buf)
                asm volatile("s_waitcnt vmcnt(12) lgkmcnt(0)" ::: "memory");
                MFMA32(aEv, kk == 0)
                BARRIER();
            }
            {                                // odd phase: use aOd, load aEv
                const int ko = kk + 1;
                const int buf = 1;           // ko odd -> buf 1
                int kk2 = ko + 2, jt2 = jt;
                if (kk2 >= KT) { kk2 -= KT; jt2 = (jt + 1) & (NJT - 1); }
                const int kna = (ko + 1 == KT) ? 0 : ko + 1;   // next A k-tile
                RD_B(buf)
                LD_A(aEv, kna)
                STAGE_B(jt2, kk2, buf)
                asm volatile("s_waitcnt vmcnt(12) lgkmcnt(0)" ::: "memory");
                MFMA32(aOd, false)
                if (ko == KT - 1) FOLD_RMAX()
                BARRIER();
            }
        }
    }

    // epilogue: drain all in-flight ops before reusing LDS
    asm volatile("s_waitcnt vmcnt(0) lgkmcnt(0)" ::: "memory");
    BARRIER();

    const float isc = 1.0f / (QSCALE * QSCALE);
    float* red = (float*)&smB[0][0];   // [2 col-waves][128 rows]
    #pragma unroll
    for (int m = 0; m < 4; ++m)
        #pragma unroll
        for (int r = 0; r < 4; ++r) {
            int v = rmax[m][r];
            int o;
            o = __shfl_xor(v, 1); if (o > v) v = o;
            o = __shfl_xor(v, 2); if (o > v) v = o;
            o = __shfl_xor(v, 4); if (o > v) v = o;
            o = __shfl_xor(v, 8); if (o > v) v = o;
            if (lm == 0) {
                const int row_l = wrow + m * 16 + (lane >> 4) * 4 + r;
                red[(wid & 1) * 128 + row_l] = (float)v * isc;
            }
        }
    BARRIER();
    if (tid < 128) {
        wmax[(size_t)split * P_DIM + i0 + tid] = fmaxf(red[tid], red[128 + tid]);
    }
}

// --- 4. loss = mean(1 - max over 4 partials) ---
__global__ void final_reduce(const float* __restrict__ wmax, float* __restrict__ out) {
    __shared__ float red[256];
    int t = threadIdx.x;
    float sum = 0.f;
    for (int i = t; i < P_DIM; i += 256) {
        float m = wmax[i];
        #pragma unroll
        for (int sp = 1; sp < 4; ++sp) m = fmaxf(m, wmax[(size_t)sp * P_DIM + i]);
        sum += 1.0f - m;
    }
    red[t] = sum;
    __syncthreads();
    for (int st = 128; st > 0; st >>= 1) {
        if (t < st) red[t] += red[t + st];
        __syncthreads();
    }
    if (t == 0) out[0] = red[0] * (1.0f / (float)P_DIM);
}

extern "C" void kernel_launch(void* const* d_in, const int* in_sizes, int n_in,
                              void* d_out, int out_size, void* d_ws, size_t ws_size,
                              hipStream_t stream) {
    const float* x = (const float*)d_in[0];
    const float* s = (const float*)d_in[1];
    float* out = (float*)d_out;
    char* ws = (char*)d_ws;

    u8* Xn = (u8*)(ws + OFF_XN);
    u8* Sn = (u8*)(ws + OFF_SN);
    float* invx = (float*)(ws + OFF_INVX);
    float* invs = (float*)(ws + OFF_INVS);
    float* wmax = (float*)(ws + OFF_MAX);

    norm_kernel<<<dim3(64, 2), 256, 0, stream>>>(x, s, invx, invs);
    tnorm_kernel<<<dim3(256, 12, 2), 256, 0, stream>>>(x, s, invx, invs, Xn, Sn);
    nnfm_gemm_max<<<dim3((P_DIM / 128) * JSPLIT), 256, 0, stream>>>(Xn, Sn, wmax);
    final_reduce<<<1, 256, 0, stream>>>(wmax, out);
}

// Round 14
// 220.508 us; speedup vs baseline: 1.9476x; 1.9476x over previous
//
#include <hip/hip_runtime.h>
#include <math.h>

// NNFM loss on MI355X.
// loss = mean_i (1 - max_j (xhat_i . shat_j)),  xhat/shat = column-normalized feats.
// R2: XOR-swizzle -> 0 conflicts. R5: fp8 BK=128. R7: i8 16x16x64.
// R8: 2 blocks/CU overlap -> 239us. R10: XCD L2-residency map -> GEMM 180us (best banked).
// R11-R13: per-phase A-direct loads failed 3 ways (VGPR cap spill; L2 latency in
//          phase wait; deep pipeline thrashing L2 -> FETCH 450MB).
// R14: A fully register-resident: 8 waves 4M x 2N (32 A-rows/wave), whole K=768
//      A-panel = 96 VGPR loaded ONCE from fragment-linear Xn (verified layout).
//      Loop touches only B: LDS reads halve (floor ~62us), LDS 32KB, no recurring
//      A traffic. 1 block/CU, grid 256, same B-DMA/swizzle/vmcnt skeleton.

#define C_DIM 768
#define P_DIM 16384
#define KT 6            // K-tiles (BK=128) : 768/128
#define NJT 64          // j-tiles per block: 8192/128
#define JSPLIT 2
#define EPSF 1e-8f
#define QSCALE 256.0f

typedef unsigned char u8;
typedef int i32x4 __attribute__((ext_vector_type(4)));

// workspace layout (bytes)
#define OFF_XN   0
#define OFF_SN   25165824UL
#define OFF_INVX 50331648UL
#define OFF_INVS 50397184UL
#define OFF_MAX  50462720UL                 // 2 * 16384 * 4

__device__ __forceinline__ void async_copy16(const void* gsrc, void* ldst) {
    __builtin_amdgcn_global_load_lds(
        (const __attribute__((address_space(1))) void*)gsrc,
        (__attribute__((address_space(3))) void*)ldst,
        16, 0, 0);
}

#define CFENCE() asm volatile("" ::: "memory")
#define BARRIER() { CFENCE(); __builtin_amdgcn_s_barrier(); CFENCE(); }

// --- 1. column L2 norms: inv = QSCALE/(||col|| + eps); one thread per column ---
__global__ void norm_kernel(const float* __restrict__ x, const float* __restrict__ s,
                            float* __restrict__ invx, float* __restrict__ invs) {
    const float* src = blockIdx.y == 0 ? x : s;
    float* dst = (blockIdx.y == 0) ? invx : invs;
    int j = blockIdx.x * 256 + threadIdx.x;        // 0..16383
    float sum = 0.f;
    for (int c = 0; c < C_DIM; ++c) {
        float v = src[(size_t)c * P_DIM + j];
        sum += v * v;
    }
    dst[j] = QSCALE / (sqrtf(sum) + EPSF);
}

// --- 2. transpose, normalize*256, round to int8 ---
// Sn (z=1): row-major [p][c] (DMA->LDS path).
// Xn (z=0): fragment-linear for direct global->VGPR MFMA A-operands:
//   byte addr = (((kt*1024 + g)*2 + ks)<<10) + lane*16 + (kb&15),
//   g = row>>4, lane = (kb>>4)*16 + (row&15). Verified (R11-R13 absmax 0.0).
__global__ void tnorm_kernel(const float* __restrict__ x, const float* __restrict__ s,
                             const float* __restrict__ invx, const float* __restrict__ invs,
                             u8* __restrict__ Xn, u8* __restrict__ Sn) {
    __shared__ float tile[64][65];
    const float* src = blockIdx.z ? s : x;
    const float* inv = blockIdx.z ? invs : invx;
    u8* dst = blockIdx.z ? Sn : Xn;
    int c0 = blockIdx.y * 64;
    int j0 = blockIdx.x * 64;
    int t = threadIdx.x;
    #pragma unroll
    for (int it = 0; it < 16; ++it) {
        int idx = it * 256 + t;
        int cr = idx >> 6, jc = idx & 63;
        tile[cr][jc] = src[(c0 + cr) * P_DIM + j0 + jc];
    }
    __syncthreads();
    const int kt = c0 >> 7;
    const int ks = (c0 >> 6) & 1;
    #pragma unroll
    for (int it = 0; it < 2; ++it) {
        int item = it * 256 + t;
        int jr = item >> 3;
        int oct = item & 7;
        float iv = inv[j0 + jr];
        unsigned long long pk = 0;
        #pragma unroll
        for (int o = 0; o < 8; ++o) {
            float v = tile[oct * 8 + o][jr] * iv;
            v = fminf(fmaxf(v, -127.0f), 127.0f);
            int q = (int)rintf(v);
            pk |= ((unsigned long long)(unsigned)(q & 0xFF)) << (8 * o);
        }
        size_t addr;
        if (blockIdx.z) {
            addr = (size_t)(j0 + jr) * C_DIM + c0 + oct * 8;
        } else {
            const int g = (j0 + jr) >> 4;
            const int lane = ((oct >> 1) << 4) + (jr & 15);
            addr = ((((size_t)kt * 1024 + g) * 2 + ks) << 10) + lane * 16 + ((oct & 1) << 3);
        }
        *(unsigned long long*)(dst + addr) = pk;
    }
}

// --- 3. 128x128-tile i8 GEMM: A register-resident (full K), B via LDS; 8 waves ---
// Wave layout 4M x 2N: wrow = (wid>>1)*32, wcol = (wid&1)*64.
// A panel/wave = 32 rows x 768 k = 24 x i32x4 = 96 VGPR, loaded once (prologue).
// Per iter: {8 ds_read_b128 B | 2 B-DMA (t+2 into live buf) | vmcnt(2) lgkmcnt(0)
//            | 16 MFMA | barrier}. 1 block/CU (grid 256), XCD residency map.
__global__ __launch_bounds__(512, 2) void nnfm_gemm_max(
    const u8* __restrict__ Xn, const u8* __restrict__ Sn,
    float* __restrict__ wmax) {
    __shared__ __align__(16) u8 smB[2][128 * 128];

    const int bid = blockIdx.x;
    const int xcd = bid & 7;
    const int idx = bid >> 3;               // 0..31
    const int iblk = xcd * 16 + (idx & 15); // A residency: 16 iblks/XCD = 1.5MB
    const int split = idx >> 4;             // 0..1
    const int i0 = iblk * 128;
    const int jbase = split * (P_DIM / JSPLIT);

    const int tid = threadIdx.x;
    const int lane = tid & 63;
    const int wid = tid >> 6;               // 0..7
    const int wrow = (wid >> 1) * 32;
    const int wcol = (wid & 1) * 64;
    const int lm = lane & 15;

    const int srow = wid * 8 + (lane >> 3);                // staging row base (0..63), +c*64
    const int scol = ((lane & 7) ^ (lane >> 3)) * 16;      // swizzled source col (bytes)
    const int kidx0 = (((lane >> 4) + 0) ^ (lane & 7)) * 16;
    const int kidx1 = (((lane >> 4) + 4) ^ (lane & 7)) * 16;

    // A chunk index g0 = iblk*8 + wrow/16 ; chunk(kt,g,ks) at ((kt*1024+g)*2+ks)<<10
    const u8* Abase = Xn + (size_t)lane * 16;
    const int g0 = iblk * 8 + (wrow >> 4);

#define STAGE_B(jt_t, kk_t, buf_t) { \
    _Pragma("unroll") \
    for (int c = 0; c < 2; ++c) \
      async_copy16(Sn + (size_t)(jbase + (jt_t) * 128 + c * 64 + srow) * C_DIM + (kk_t) * 128 + scol, \
                   &smB[buf_t][(c * 64 + wid * 8) * 128]); }

#define RD_B(BUF) { \
    _Pragma("unroll") \
    for (int n = 0; n < 4; ++n) { \
      bF[n][0] = *(const i32x4*)&smB[BUF][(wcol + n * 16 + lm) * 128 + kidx0]; \
      bF[n][1] = *(const i32x4*)&smB[BUF][(wcol + n * 16 + lm) * 128 + kidx1]; \
    } }

#define MFMA16(KK, DOZERO) { \
    if (DOZERO) { \
      _Pragma("unroll") \
      for (int m = 0; m < 2; ++m) \
        _Pragma("unroll") \
        for (int n = 0; n < 4; ++n) \
          acc[m][n] = i32x4{0, 0, 0, 0}; \
    } \
    __builtin_amdgcn_s_setprio(1); \
    _Pragma("unroll") \
    for (int ks = 0; ks < 2; ++ks) \
      _Pragma("unroll") \
      for (int m = 0; m < 2; ++m) \
        _Pragma("unroll") \
        for (int n = 0; n < 4; ++n) \
          acc[m][n] = __builtin_amdgcn_mfma_i32_16x16x64_i8(aR[KK][m][ks], bF[n][ks], acc[m][n], 0, 0, 0); \
    __builtin_amdgcn_s_setprio(0); }

    i32x4 acc[2][4];
    i32x4 aR[KT][2][2];                    // 24 x i32x4 = 96 VGPR, static-indexed
    i32x4 bF[4][2];
    int rmax[2][4];
    #pragma unroll
    for (int m = 0; m < 2; ++m)
        #pragma unroll
        for (int r = 0; r < 4; ++r) rmax[m][r] = (int)0x80000000;

    // prologue: B(0)->buf0, A(all K) once, B(1)->buf1 LAST (stays in flight);
    // vmcnt(2) drains B(0)+A, keeps B(1).
    STAGE_B(0, 0, 0);
    #pragma unroll
    for (int kk = 0; kk < KT; ++kk)
        #pragma unroll
        for (int m = 0; m < 2; ++m)
            #pragma unroll
            for (int ks = 0; ks < 2; ++ks)
                aR[kk][m][ks] = *(const i32x4*)(Abase +
                    ((((size_t)kk * 1024 + g0 + m) * 2 + ks) << 10));
    STAGE_B(0, 1, 1);
    asm volatile("s_waitcnt vmcnt(2)" ::: "memory");
    BARRIER();

    for (int jt = 0; jt < NJT; ++jt) {
        #pragma unroll
        for (int kk = 0; kk < KT; ++kk) {
            const int buf = kk & 1;
            int kk2 = kk + 2, jt2 = jt;
            if (kk2 >= KT) { kk2 -= KT; jt2 = (jt + 1) & (NJT - 1); }

            RD_B(buf)
            STAGE_B(jt2, kk2, buf)           // into live buf after its reads
            asm volatile("s_waitcnt vmcnt(2) lgkmcnt(0)" ::: "memory");
            MFMA16(kk, kk == 0)
            if (kk == KT - 1) {
                #pragma unroll
                for (int m = 0; m < 2; ++m)
                    #pragma unroll
                    for (int r = 0; r < 4; ++r) {
                        int mx = acc[m][0][r];
                        #pragma unroll
                        for (int n = 1; n < 4; ++n)
                            if (acc[m][n][r] > mx) mx = acc[m][n][r];
                        if (mx > rmax[m][r]) rmax[m][r] = mx;
                    }
            }
            BARRIER();
        }
    }

    // epilogue: drain all in-flight DMA before reusing LDS
    asm volatile("s_waitcnt vmcnt(0) lgkmcnt(0)" ::: "memory");
    BARRIER();

    const float isc = 1.0f / (QSCALE * QSCALE);
    float* red = (float*)&smB[0][0];   // [2 col-groups][128 rows]
    #pragma unroll
    for (int m = 0; m < 2; ++m)
        #pragma unroll
        for (int r = 0; r < 4; ++r) {
            int v = rmax[m][r];
            int o;
            o = __shfl_xor(v, 1); if (o > v) v = o;
            o = __shfl_xor(v, 2); if (o > v) v = o;
            o = __shfl_xor(v, 4); if (o > v) v = o;
            o = __shfl_xor(v, 8); if (o > v) v = o;
            if (lm == 0) {
                const int row_l = wrow + m * 16 + (lane >> 4) * 4 + r;
                red[(wid & 1) * 128 + row_l] = (float)v * isc;
            }
        }
    BARRIER();
    if (tid < 128) {
        wmax[(size_t)split * P_DIM + i0 + tid] = fmaxf(red[tid], red[128 + tid]);
    }
}

// --- 4. loss = mean(1 - max over 2 partials) ---
__global__ void final_reduce(const float* __restrict__ wmax, float* __restrict__ out) {
    __shared__ float red[256];
    int t = threadIdx.x;
    float sum = 0.f;
    for (int i = t; i < P_DIM; i += 256) {
        float m = fmaxf(wmax[i], wmax[(size_t)P_DIM + i]);
        sum += 1.0f - m;
    }
    red[t] = sum;
    __syncthreads();
    for (int st = 128; st > 0; st >>= 1) {
        if (t < st) red[t] += red[t + st];
        __syncthreads();
    }
    if (t == 0) out[0] = red[0] * (1.0f / (float)P_DIM);
}

extern "C" void kernel_launch(void* const* d_in, const int* in_sizes, int n_in,
                              void* d_out, int out_size, void* d_ws, size_t ws_size,
                              hipStream_t stream) {
    const float* x = (const float*)d_in[0];
    const float* s = (const float*)d_in[1];
    float* out = (float*)d_out;
    char* ws = (char*)d_ws;

    u8* Xn = (u8*)(ws + OFF_XN);
    u8* Sn = (u8*)(ws + OFF_SN);
    float* invx = (float*)(ws + OFF_INVX);
    float* invs = (float*)(ws + OFF_INVS);
    float* wmax = (float*)(ws + OFF_MAX);

    norm_kernel<<<dim3(64, 2), 256, 0, stream>>>(x, s, invx, invs);
    tnorm_kernel<<<dim3(256, 12, 2), 256, 0, stream>>>(x, s, invx, invs, Xn, Sn);
    nnfm_gemm_max<<<dim3((P_DIM / 128) * JSPLIT), 512, 0, stream>>>(Xn, Sn, wmax);
    final_reduce<<<1, 256, 0, stream>>>(wmax, out);
}

// Round 15
// 214.549 us; speedup vs baseline: 2.0017x; 1.0278x over previous
//
#include <hip/hip_runtime.h>
#include <math.h>

// NNFM loss on MI355X.
// loss = mean_i (1 - max_j (xhat_i . shat_j)),  xhat/shat = column-normalized feats.
// R2: XOR-swizzle -> 0 conflicts. R5: fp8 BK=128. R7: i8 16x16x64.
// R8: 2 blocks/CU. R10: XCD L2-residency map -> FETCH 56MB.
// R14: A register-resident (96 VGPR, loaded once), B-only LDS -> GEMM 167us,
//      220us total. Walls: LDS 770cyc/iter, MFMA 653, measured 1044 -> ~275cyc/iter
//      of barrier+drain events (384 events).
// R15: (a) j-PAIR per barrier window: 2 B tiles, 2 acc sets, 4-slot LDS (64KB),
//          stage-into-live-slot at pair granularity, vmcnt(4) -> 192 events;
//      (b) norm split into c-chunk partials (grid 384) + tiny combine.

#define C_DIM 768
#define P_DIM 16384
#define KT 6            // K-tiles (BK=128) : 768/128
#define NJP 32          // j-PAIRS per block: 64 tiles / 2
#define JSPLIT 2
#define EPSF 1e-8f
#define QSCALE 256.0f

typedef unsigned char u8;
typedef int i32x4 __attribute__((ext_vector_type(4)));

// workspace layout (bytes); high-water 50987008 == R1/R2-proven
#define OFF_XN   0
#define OFF_SN   25165824UL
#define OFF_INVX 50331648UL
#define OFF_INVS 50397184UL
#define OFF_MAX  50462720UL                 // 2 * 16384 * 4 = 131072
#define OFF_PART 50593792UL                 // 2 * 3 * 16384 * 4 = 393216 -> end 50987008

__device__ __forceinline__ void async_copy16(const void* gsrc, void* ldst) {
    __builtin_amdgcn_global_load_lds(
        (const __attribute__((address_space(1))) void*)gsrc,
        (__attribute__((address_space(3))) void*)ldst,
        16, 0, 0);
}

#define CFENCE() asm volatile("" ::: "memory")
#define BARRIER() { CFENCE(); __builtin_amdgcn_s_barrier(); CFENCE(); }

// --- 1a. column sum-of-squares partials over c-chunks of 256 ---
__global__ void norm1_kernel(const float* __restrict__ x, const float* __restrict__ s,
                             float* __restrict__ part) {
    const float* src = blockIdx.y == 0 ? x : s;
    int j = blockIdx.x * 256 + threadIdx.x;
    int c0 = blockIdx.z * 256;
    float sum = 0.f;
    for (int c = c0; c < c0 + 256; ++c) {
        float v = src[(size_t)c * P_DIM + j];
        sum += v * v;
    }
    part[((size_t)blockIdx.y * 3 + blockIdx.z) * P_DIM + j] = sum;
}

// --- 1b. combine partials -> inv = QSCALE/(||col|| + eps) ---
__global__ void norm2_kernel(const float* __restrict__ part,
                             float* __restrict__ invx, float* __restrict__ invs) {
    int j = blockIdx.x * 256 + threadIdx.x;
    int inp = blockIdx.y;
    float s = part[((size_t)inp * 3 + 0) * P_DIM + j]
            + part[((size_t)inp * 3 + 1) * P_DIM + j]
            + part[((size_t)inp * 3 + 2) * P_DIM + j];
    float* dst = inp ? invs : invx;
    dst[j] = QSCALE / (sqrtf(s) + EPSF);
}

// --- 2. transpose, normalize*256, round to int8 ---
// Sn (z=1): row-major [p][c] (DMA->LDS path).
// Xn (z=0): fragment-linear for direct global->VGPR MFMA A-operands:
//   byte addr = (((kt*1024 + g)*2 + ks)<<10) + lane*16 + (kb&15). Verified R11-R14.
__global__ void tnorm_kernel(const float* __restrict__ x, const float* __restrict__ s,
                             const float* __restrict__ invx, const float* __restrict__ invs,
                             u8* __restrict__ Xn, u8* __restrict__ Sn) {
    __shared__ float tile[64][65];
    const float* src = blockIdx.z ? s : x;
    const float* inv = blockIdx.z ? invs : invx;
    u8* dst = blockIdx.z ? Sn : Xn;
    int c0 = blockIdx.y * 64;
    int j0 = blockIdx.x * 64;
    int t = threadIdx.x;
    #pragma unroll
    for (int it = 0; it < 16; ++it) {
        int idx = it * 256 + t;
        int cr = idx >> 6, jc = idx & 63;
        tile[cr][jc] = src[(c0 + cr) * P_DIM + j0 + jc];
    }
    __syncthreads();
    const int kt = c0 >> 7;
    const int ks = (c0 >> 6) & 1;
    #pragma unroll
    for (int it = 0; it < 2; ++it) {
        int item = it * 256 + t;
        int jr = item >> 3;
        int oct = item & 7;
        float iv = inv[j0 + jr];
        unsigned long long pk = 0;
        #pragma unroll
        for (int o = 0; o < 8; ++o) {
            float v = tile[oct * 8 + o][jr] * iv;
            v = fminf(fmaxf(v, -127.0f), 127.0f);
            int q = (int)rintf(v);
            pk |= ((unsigned long long)(unsigned)(q & 0xFF)) << (8 * o);
        }
        size_t addr;
        if (blockIdx.z) {
            addr = (size_t)(j0 + jr) * C_DIM + c0 + oct * 8;
        } else {
            const int g = (j0 + jr) >> 4;
            const int lane = ((oct >> 1) << 4) + (jr & 15);
            addr = ((((size_t)kt * 1024 + g) * 2 + ks) << 10) + lane * 16 + ((oct & 1) << 3);
        }
        *(unsigned long long*)(dst + addr) = pk;
    }
}

// --- 3. 128x128-tile i8 GEMM: A register-resident, B via 4-slot LDS; j-pair windows ---
__global__ __launch_bounds__(512, 2) void nnfm_gemm_max(
    const u8* __restrict__ Xn, const u8* __restrict__ Sn,
    float* __restrict__ wmax) {
    __shared__ __align__(16) u8 smB[2][2][128 * 128];   // [pair][tile] = 64KB

    const int bid = blockIdx.x;
    const int xcd = bid & 7;
    const int idx = bid >> 3;               // 0..31
    const int iblk = xcd * 16 + (idx & 15); // A residency: 16 iblks/XCD = 1.5MB
    const int split = idx >> 4;             // 0..1
    const int i0 = iblk * 128;
    const int jbase = split * (P_DIM / JSPLIT);

    const int tid = threadIdx.x;
    const int lane = tid & 63;
    const int wid = tid >> 6;               // 0..7
    const int wrow = (wid >> 1) * 32;
    const int wcol = (wid & 1) * 64;
    const int lm = lane & 15;

    const int srow = wid * 8 + (lane >> 3);                // staging row base, +c*64
    const int scol = ((lane & 7) ^ (lane >> 3)) * 16;      // swizzled source col (bytes)
    const int kidx0 = (((lane >> 4) + 0) ^ (lane & 7)) * 16;
    const int kidx1 = (((lane >> 4) + 4) ^ (lane & 7)) * 16;

    const u8* Abase = Xn + (size_t)lane * 16;
    const int g0 = iblk * 8 + (wrow >> 4);

#define STAGE_B1(jt_t, kk_t, PAIR, T) { \
    _Pragma("unroll") \
    for (int c = 0; c < 2; ++c) \
      async_copy16(Sn + (size_t)(jbase + (jt_t) * 128 + c * 64 + srow) * C_DIM + (kk_t) * 128 + scol, \
                   &smB[PAIR][T][(c * 64 + wid * 8) * 128]); }

#define RD_B(PAIR, T) { \
    _Pragma("unroll") \
    for (int n = 0; n < 4; ++n) { \
      bF[n][0] = *(const i32x4*)&smB[PAIR][T][(wcol + n * 16 + lm) * 128 + kidx0]; \
      bF[n][1] = *(const i32x4*)&smB[PAIR][T][(wcol + n * 16 + lm) * 128 + kidx1]; \
    } }

#define MFMA16(ACC, KK, DOZERO) { \
    if (DOZERO) { \
      _Pragma("unroll") \
      for (int m = 0; m < 2; ++m) \
        _Pragma("unroll") \
        for (int n = 0; n < 4; ++n) \
          ACC[m][n] = i32x4{0, 0, 0, 0}; \
    } \
    __builtin_amdgcn_s_setprio(1); \
    _Pragma("unroll") \
    for (int ks = 0; ks < 2; ++ks) \
      _Pragma("unroll") \
      for (int m = 0; m < 2; ++m) \
        _Pragma("unroll") \
        for (int n = 0; n < 4; ++n) \
          ACC[m][n] = __builtin_amdgcn_mfma_i32_16x16x64_i8(aR[KK][m][ks], bF[n][ks], ACC[m][n], 0, 0, 0); \
    __builtin_amdgcn_s_setprio(0); }

#define FOLD(ACC) { \
    _Pragma("unroll") \
    for (int m = 0; m < 2; ++m) \
      _Pragma("unroll") \
      for (int r = 0; r < 4; ++r) { \
        int mx = ACC[m][0][r]; \
        _Pragma("unroll") \
        for (int n = 1; n < 4; ++n) \
          if (ACC[m][n][r] > mx) mx = ACC[m][n][r]; \
        if (mx > rmax[m][r]) rmax[m][r] = mx; \
      } }

    i32x4 acc0[2][4], acc1[2][4];
    i32x4 aR[KT][2][2];                    // 96 VGPR, static-indexed
    i32x4 bF[4][2];
    int rmax[2][4];
    #pragma unroll
    for (int m = 0; m < 2; ++m)
        #pragma unroll
        for (int r = 0; r < 4; ++r) rmax[m][r] = (int)0x80000000;

    // prologue: W0 pair (4 DMA), A panel (24 loads), W1 pair (4 DMA);
    // vmcnt(4) drains W0+A, keeps W1 in flight.
    STAGE_B1(0, 0, 0, 0); STAGE_B1(1, 0, 0, 1);
    #pragma unroll
    for (int kk = 0; kk < KT; ++kk)
        #pragma unroll
        for (int m = 0; m < 2; ++m)
            #pragma unroll
            for (int ks = 0; ks < 2; ++ks)
                aR[kk][m][ks] = *(const i32x4*)(Abase +
                    ((((size_t)kk * 1024 + g0 + m) * 2 + ks) << 10));
    STAGE_B1(0, 1, 1, 0); STAGE_B1(1, 1, 1, 1);
    asm volatile("s_waitcnt vmcnt(4)" ::: "memory");
    BARRIER();

    for (int jp = 0; jp < NJP; ++jp) {
        #pragma unroll
        for (int kk = 0; kk < KT; ++kk) {
            const int pair = kk & 1;        // window parity (6*jp even)
            int kk2 = kk + 2, jp2 = jp;
            if (kk2 >= KT) { kk2 -= KT; jp2 = (jp + 1) & (NJP - 1); }
            const bool z = (kk == 0), rx = (kk == KT - 1);

            RD_B(pair, 0)
            STAGE_B1(jp2 * 2, kk2, pair, 0)       // slot dead after its reads
            MFMA16(acc0, kk, z)
            RD_B(pair, 1)
            STAGE_B1(jp2 * 2 + 1, kk2, pair, 1)
            MFMA16(acc1, kk, z)
            if (rx) { FOLD(acc0) FOLD(acc1) }
            asm volatile("s_waitcnt vmcnt(4) lgkmcnt(0)" ::: "memory");
            BARRIER();
        }
    }

    // epilogue: drain all in-flight DMA before reusing LDS
    asm volatile("s_waitcnt vmcnt(0) lgkmcnt(0)" ::: "memory");
    BARRIER();

    const float isc = 1.0f / (QSCALE * QSCALE);
    float* red = (float*)&smB[0][0][0];   // [2 col-groups][128 rows]
    #pragma unroll
    for (int m = 0; m < 2; ++m)
        #pragma unroll
        for (int r = 0; r < 4; ++r) {
            int v = rmax[m][r];
            int o;
            o = __shfl_xor(v, 1); if (o > v) v = o;
            o = __shfl_xor(v, 2); if (o > v) v = o;
            o = __shfl_xor(v, 4); if (o > v) v = o;
            o = __shfl_xor(v, 8); if (o > v) v = o;
            if (lm == 0) {
                const int row_l = wrow + m * 16 + (lane >> 4) * 4 + r;
                red[(wid & 1) * 128 + row_l] = (float)v * isc;
            }
        }
    BARRIER();
    if (tid < 128) {
        wmax[(size_t)split * P_DIM + i0 + tid] = fmaxf(red[tid], red[128 + tid]);
    }
}

// --- 4. loss = mean(1 - max over 2 partials) ---
__global__ void final_reduce(const float* __restrict__ wmax, float* __restrict__ out) {
    __shared__ float red[256];
    int t = threadIdx.x;
    float sum = 0.f;
    for (int i = t; i < P_DIM; i += 256) {
        float m = fmaxf(wmax[i], wmax[(size_t)P_DIM + i]);
        sum += 1.0f - m;
    }
    red[t] = sum;
    __syncthreads();
    for (int st = 128; st > 0; st >>= 1) {
        if (t < st) red[t] += red[t + st];
        __syncthreads();
    }
    if (t == 0) out[0] = red[0] * (1.0f / (float)P_DIM);
}

extern "C" void kernel_launch(void* const* d_in, const int* in_sizes, int n_in,
                              void* d_out, int out_size, void* d_ws, size_t ws_size,
                              hipStream_t stream) {
    const float* x = (const float*)d_in[0];
    const float* s = (const float*)d_in[1];
    float* out = (float*)d_out;
    char* ws = (char*)d_ws;

    u8* Xn = (u8*)(ws + OFF_XN);
    u8* Sn = (u8*)(ws + OFF_SN);
    float* invx = (float*)(ws + OFF_INVX);
    float* invs = (float*)(ws + OFF_INVS);
    float* wmax = (float*)(ws + OFF_MAX);
    float* part = (float*)(ws + OFF_PART);

    norm1_kernel<<<dim3(64, 2, 3), 256, 0, stream>>>(x, s, part);
    norm2_kernel<<<dim3(64, 2), 256, 0, stream>>>(part, invx, invs);
    tnorm_kernel<<<dim3(256, 12, 2), 256, 0, stream>>>(x, s, invx, invs, Xn, Sn);
    nnfm_gemm_max<<<dim3((P_DIM / 128) * JSPLIT), 512, 0, stream>>>(Xn, Sn, wmax);
    final_reduce<<<1, 256, 0, stream>>>(wmax, out);
}

// Round 16
// 214.520 us; speedup vs baseline: 2.0020x; 1.0001x over previous
//
#include <hip/hip_runtime.h>
#include <math.h>

// NNFM loss on MI355X.
// loss = mean_i (1 - max_j (xhat_i . shat_j)),  xhat/shat = column-normalized feats.
// R2: XOR-swizzle -> 0 conflicts. R5: fp8 BK=128. R7: i8 16x16x64.
// R8: 2 blocks/CU overlap (+37%). R10: XCD L2-residency map -> FETCH 56MB.
// R14: A register-resident (96 VGPR once), B-only LDS -> GEMM 167us.
// R15: j-pair windows -> neutral; analysis: near per-CU LDS-BW wall (1540cyc reads
//      vs 2062 measured) AND grid 256 = only 1 block/CU (no cross-block overlap).
// R16: JSPLIT=4 -> grid 512 = 2 blocks/CU (LDS 2x64KB, VGPR 116 fits 4 waves/SIMD);
//      second block fills barrier/drain gaps. norm2 folded into tnorm.
//      wmax aliased over PART region (disjoint lifetimes) - stays under high-water.

#define C_DIM 768
#define P_DIM 16384
#define KT 6            // K-tiles (BK=128) : 768/128
#define NJP 16          // j-PAIRS per block: 4096/128/2
#define JSPLIT 4
#define EPSF 1e-8f
#define QSCALE 256.0f

typedef unsigned char u8;
typedef int i32x4 __attribute__((ext_vector_type(4)));

// workspace layout (bytes); high-water 50855936 < proven 50987008
#define OFF_XN   0
#define OFF_SN   25165824UL
#define OFF_INVX 50331648UL
#define OFF_INVS 50397184UL
#define OFF_PART 50462720UL                 // 2*3*16384*4 = 393216 (norm phase)
#define OFF_MAX  50462720UL                 // 4*16384*4 = 262144 (GEMM phase, aliased)

__device__ __forceinline__ void async_copy16(const void* gsrc, void* ldst) {
    __builtin_amdgcn_global_load_lds(
        (const __attribute__((address_space(1))) void*)gsrc,
        (__attribute__((address_space(3))) void*)ldst,
        16, 0, 0);
}

#define CFENCE() asm volatile("" ::: "memory")
#define BARRIER() { CFENCE(); __builtin_amdgcn_s_barrier(); CFENCE(); }

// --- 1. column sum-of-squares partials over c-chunks of 256 ---
__global__ void norm1_kernel(const float* __restrict__ x, const float* __restrict__ s,
                             float* __restrict__ part) {
    const float* src = blockIdx.y == 0 ? x : s;
    int j = blockIdx.x * 256 + threadIdx.x;
    int c0 = blockIdx.z * 256;
    float sum = 0.f;
    for (int c = c0; c < c0 + 256; ++c) {
        float v = src[(size_t)c * P_DIM + j];
        sum += v * v;
    }
    part[((size_t)blockIdx.y * 3 + blockIdx.z) * P_DIM + j] = sum;
}

// --- 2. transpose, normalize*256 (inv computed inline from partials), int8 ---
// Sn (z=1): row-major [p][c]. Xn (z=0): fragment-linear (verified R11-R15):
//   byte addr = (((kt*1024 + g)*2 + ks)<<10) + lane*16 + (kb&15).
__global__ void tnorm_kernel(const float* __restrict__ x, const float* __restrict__ s,
                             const float* __restrict__ part,
                             u8* __restrict__ Xn, u8* __restrict__ Sn) {
    __shared__ float tile[64][65];
    __shared__ float invsh[64];
    const float* src = blockIdx.z ? s : x;
    u8* dst = blockIdx.z ? Sn : Xn;
    int c0 = blockIdx.y * 64;
    int j0 = blockIdx.x * 64;
    int t = threadIdx.x;
    if (t < 64) {
        const float* pp = part + (size_t)blockIdx.z * 3 * P_DIM + j0 + t;
        float ss = pp[0] + pp[P_DIM] + pp[2 * P_DIM];
        invsh[t] = QSCALE / (sqrtf(ss) + EPSF);
    }
    #pragma unroll
    for (int it = 0; it < 16; ++it) {
        int idx = it * 256 + t;
        int cr = idx >> 6, jc = idx & 63;
        tile[cr][jc] = src[(c0 + cr) * P_DIM + j0 + jc];
    }
    __syncthreads();
    const int kt = c0 >> 7;
    const int ks = (c0 >> 6) & 1;
    #pragma unroll
    for (int it = 0; it < 2; ++it) {
        int item = it * 256 + t;
        int jr = item >> 3;
        int oct = item & 7;
        float iv = invsh[jr];
        unsigned long long pk = 0;
        #pragma unroll
        for (int o = 0; o < 8; ++o) {
            float v = tile[oct * 8 + o][jr] * iv;
            v = fminf(fmaxf(v, -127.0f), 127.0f);
            int q = (int)rintf(v);
            pk |= ((unsigned long long)(unsigned)(q & 0xFF)) << (8 * o);
        }
        size_t addr;
        if (blockIdx.z) {
            addr = (size_t)(j0 + jr) * C_DIM + c0 + oct * 8;
        } else {
            const int g = (j0 + jr) >> 4;
            const int lane = ((oct >> 1) << 4) + (jr & 15);
            addr = ((((size_t)kt * 1024 + g) * 2 + ks) << 10) + lane * 16 + ((oct & 1) << 3);
        }
        *(unsigned long long*)(dst + addr) = pk;
    }
}

// --- 3. 128x128-tile i8 GEMM: A register-resident, B via 4-slot LDS; 2 blocks/CU ---
__global__ __launch_bounds__(512, 2) void nnfm_gemm_max(
    const u8* __restrict__ Xn, const u8* __restrict__ Sn,
    float* __restrict__ wmax) {
    __shared__ __align__(16) u8 smB[2][2][128 * 128];   // [pair][tile] = 64KB

    const int bid = blockIdx.x;
    const int xcd = bid & 7;
    const int idx = bid >> 3;               // 0..63
    const int iblk = xcd * 16 + (idx & 15); // A residency: 16 iblks/XCD = 1.5MB
    const int split = idx >> 4;             // 0..3
    const int i0 = iblk * 128;
    const int jbase = split * (P_DIM / JSPLIT);

    const int tid = threadIdx.x;
    const int lane = tid & 63;
    const int wid = tid >> 6;               // 0..7
    const int wrow = (wid >> 1) * 32;
    const int wcol = (wid & 1) * 64;
    const int lm = lane & 15;

    const int srow = wid * 8 + (lane >> 3);                // staging row base, +c*64
    const int scol = ((lane & 7) ^ (lane >> 3)) * 16;      // swizzled source col (bytes)
    const int kidx0 = (((lane >> 4) + 0) ^ (lane & 7)) * 16;
    const int kidx1 = (((lane >> 4) + 4) ^ (lane & 7)) * 16;

    const u8* Abase = Xn + (size_t)lane * 16;
    const int g0 = iblk * 8 + (wrow >> 4);

#define STAGE_B1(jt_t, kk_t, PAIR, T) { \
    _Pragma("unroll") \
    for (int c = 0; c < 2; ++c) \
      async_copy16(Sn + (size_t)(jbase + (jt_t) * 128 + c * 64 + srow) * C_DIM + (kk_t) * 128 + scol, \
                   &smB[PAIR][T][(c * 64 + wid * 8) * 128]); }

#define RD_B(PAIR, T) { \
    _Pragma("unroll") \
    for (int n = 0; n < 4; ++n) { \
      bF[n][0] = *(const i32x4*)&smB[PAIR][T][(wcol + n * 16 + lm) * 128 + kidx0]; \
      bF[n][1] = *(const i32x4*)&smB[PAIR][T][(wcol + n * 16 + lm) * 128 + kidx1]; \
    } }

#define MFMA16(ACC, KK, DOZERO) { \
    if (DOZERO) { \
      _Pragma("unroll") \
      for (int m = 0; m < 2; ++m) \
        _Pragma("unroll") \
        for (int n = 0; n < 4; ++n) \
          ACC[m][n] = i32x4{0, 0, 0, 0}; \
    } \
    __builtin_amdgcn_s_setprio(1); \
    _Pragma("unroll") \
    for (int ks = 0; ks < 2; ++ks) \
      _Pragma("unroll") \
      for (int m = 0; m < 2; ++m) \
        _Pragma("unroll") \
        for (int n = 0; n < 4; ++n) \
          ACC[m][n] = __builtin_amdgcn_mfma_i32_16x16x64_i8(aR[KK][m][ks], bF[n][ks], ACC[m][n], 0, 0, 0); \
    __builtin_amdgcn_s_setprio(0); }

#define FOLD(ACC) { \
    _Pragma("unroll") \
    for (int m = 0; m < 2; ++m) \
      _Pragma("unroll") \
      for (int r = 0; r < 4; ++r) { \
        int mx = ACC[m][0][r]; \
        _Pragma("unroll") \
        for (int n = 1; n < 4; ++n) \
          if (ACC[m][n][r] > mx) mx = ACC[m][n][r]; \
        if (mx > rmax[m][r]) rmax[m][r] = mx; \
      } }

    i32x4 acc0[2][4], acc1[2][4];
    i32x4 aR[KT][2][2];                    // 96 VGPR, static-indexed
    i32x4 bF[4][2];
    int rmax[2][4];
    #pragma unroll
    for (int m = 0; m < 2; ++m)
        #pragma unroll
        for (int r = 0; r < 4; ++r) rmax[m][r] = (int)0x80000000;

    // prologue: W0 pair (4 DMA), A panel (24 loads), W1 pair (4 DMA);
    // vmcnt(4) drains W0+A, keeps W1 in flight.
    STAGE_B1(0, 0, 0, 0); STAGE_B1(1, 0, 0, 1);
    #pragma unroll
    for (int kk = 0; kk < KT; ++kk)
        #pragma unroll
        for (int m = 0; m < 2; ++m)
            #pragma unroll
            for (int ks = 0; ks < 2; ++ks)
                aR[kk][m][ks] = *(const i32x4*)(Abase +
                    ((((size_t)kk * 1024 + g0 + m) * 2 + ks) << 10));
    STAGE_B1(0, 1, 1, 0); STAGE_B1(1, 1, 1, 1);
    asm volatile("s_waitcnt vmcnt(4)" ::: "memory");
    BARRIER();

    for (int jp = 0; jp < NJP; ++jp) {
        #pragma unroll
        for (int kk = 0; kk < KT; ++kk) {
            const int pair = kk & 1;        // window parity (6*jp even)
            int kk2 = kk + 2, jp2 = jp;
            if (kk2 >= KT) { kk2 -= KT; jp2 = (jp + 1) & (NJP - 1); }
            const bool z = (kk == 0), rx = (kk == KT - 1);

            RD_B(pair, 0)
            STAGE_B1(jp2 * 2, kk2, pair, 0)       // slot dead after its reads
            MFMA16(acc0, kk, z)
            RD_B(pair, 1)
            STAGE_B1(jp2 * 2 + 1, kk2, pair, 1)
            MFMA16(acc1, kk, z)
            if (rx) { FOLD(acc0) FOLD(acc1) }
            asm volatile("s_waitcnt vmcnt(4) lgkmcnt(0)" ::: "memory");
            BARRIER();
        }
    }

    // epilogue: drain all in-flight DMA before reusing LDS
    asm volatile("s_waitcnt vmcnt(0) lgkmcnt(0)" ::: "memory");
    BARRIER();

    const float isc = 1.0f / (QSCALE * QSCALE);
    float* red = (float*)&smB[0][0][0];   // [2 col-groups][128 rows]
    #pragma unroll
    for (int m = 0; m < 2; ++m)
        #pragma unroll
        for (int r = 0; r < 4; ++r) {
            int v = rmax[m][r];
            int o;
            o = __shfl_xor(v, 1); if (o > v) v = o;
            o = __shfl_xor(v, 2); if (o > v) v = o;
            o = __shfl_xor(v, 4); if (o > v) v = o;
            o = __shfl_xor(v, 8); if (o > v) v = o;
            if (lm == 0) {
                const int row_l = wrow + m * 16 + (lane >> 4) * 4 + r;
                red[(wid & 1) * 128 + row_l] = (float)v * isc;
            }
        }
    BARRIER();
    if (tid < 128) {
        wmax[(size_t)split * P_DIM + i0 + tid] = fmaxf(red[tid], red[128 + tid]);
    }
}

// --- 4. loss = mean(1 - max over 4 partials) ---
__global__ void final_reduce(const float* __restrict__ wmax, float* __restrict__ out) {
    __shared__ float red[256];
    int t = threadIdx.x;
    float sum = 0.f;
    for (int i = t; i < P_DIM; i += 256) {
        float m = wmax[i];
        #pragma unroll
        for (int sp = 1; sp < 4; ++sp) m = fmaxf(m, wmax[(size_t)sp * P_DIM + i]);
        sum += 1.0f - m;
    }
    red[t] = sum;
    __syncthreads();
    for (int st = 128; st > 0; st >>= 1) {
        if (t < st) red[t] += red[t + st];
        __syncthreads();
    }
    if (t == 0) out[0] = red[0] * (1.0f / (float)P_DIM);
}

extern "C" void kernel_launch(void* const* d_in, const int* in_sizes, int n_in,
                              void* d_out, int out_size, void* d_ws, size_t ws_size,
                              hipStream_t stream) {
    const float* x = (const float*)d_in[0];
    const float* s = (const float*)d_in[1];
    float* out = (float*)d_out;
    char* ws = (char*)d_ws;

    u8* Xn = (u8*)(ws + OFF_XN);
    u8* Sn = (u8*)(ws + OFF_SN);
    float* part = (float*)(ws + OFF_PART);
    float* wmax = (float*)(ws + OFF_MAX);

    norm1_kernel<<<dim3(64, 2, 3), 256, 0, stream>>>(x, s, part);
    tnorm_kernel<<<dim3(256, 12, 2), 256, 0, stream>>>(x, s, part, Xn, Sn);
    nnfm_gemm_max<<<dim3((P_DIM / 128) * JSPLIT), 512, 0, stream>>>(Xn, Sn, wmax);
    final_reduce<<<1, 256, 0, stream>>>(wmax, out);
}

// Round 17
// 210.445 us; speedup vs baseline: 2.0407x; 1.0194x over previous
//
#include <hip/hip_runtime.h>
#include <math.h>

// NNFM loss on MI355X.
// loss = mean_i (1 - max_j (xhat_i . shat_j)),  xhat/shat = column-normalized feats.
// R2: XOR-swizzle. R7: i8 16x16x64. R8: 2 blocks/CU (+37%). R10: XCD residency map.
// R14: A register-resident -> GEMM 167us. R15/R16: j-pair + JSPLIT=4 neutral:
//      116VGPR+64AGPR ~ 192/wave -> 512-thread blocks can NEVER co-reside 2/CU.
// R17: 256-thread blocks (4 waves, 1 wave/SIMD): wave = 32 rows x ALL 128 cols
//      (aR 96 + bF 32 + acc 64 AGPR ~ 220/wave; 2 blocks/CU fit: regs 2x256<=512,
//      LDS 2x32KB). Independent blocks fill each other's barrier/drain gaps.
//      Window split by ks keeps all slot reads before its re-stage (proven order).

#define C_DIM 768
#define P_DIM 16384
#define KT 6            // K-tiles (BK=128) : 768/128
#define NJT 32          // j-tiles per block: 4096/128
#define JSPLIT 4
#define EPSF 1e-8f
#define QSCALE 256.0f

typedef unsigned char u8;
typedef int i32x4 __attribute__((ext_vector_type(4)));

// workspace layout (bytes); high-water 50855936 < proven 50987008
#define OFF_XN   0
#define OFF_SN   25165824UL
#define OFF_PART 50462720UL                 // 2*3*16384*4 = 393216 (norm phase)
#define OFF_MAX  50462720UL                 // 4*16384*4 = 262144 (GEMM phase, aliased)

__device__ __forceinline__ void async_copy16(const void* gsrc, void* ldst) {
    __builtin_amdgcn_global_load_lds(
        (const __attribute__((address_space(1))) void*)gsrc,
        (__attribute__((address_space(3))) void*)ldst,
        16, 0, 0);
}

#define CFENCE() asm volatile("" ::: "memory")
#define BARRIER() { CFENCE(); __builtin_amdgcn_s_barrier(); CFENCE(); }

// --- 1. column sum-of-squares partials over c-chunks of 256 ---
__global__ void norm1_kernel(const float* __restrict__ x, const float* __restrict__ s,
                             float* __restrict__ part) {
    const float* src = blockIdx.y == 0 ? x : s;
    int j = blockIdx.x * 256 + threadIdx.x;
    int c0 = blockIdx.z * 256;
    float sum = 0.f;
    for (int c = c0; c < c0 + 256; ++c) {
        float v = src[(size_t)c * P_DIM + j];
        sum += v * v;
    }
    part[((size_t)blockIdx.y * 3 + blockIdx.z) * P_DIM + j] = sum;
}

// --- 2. transpose, normalize*256 (inv inline from partials), round to int8 ---
// Sn (z=1): row-major [p][c]. Xn (z=0): fragment-linear (verified R11-R16):
//   byte addr = (((kt*1024 + g)*2 + ks)<<10) + lane*16 + (kb&15).
__global__ void tnorm_kernel(const float* __restrict__ x, const float* __restrict__ s,
                             const float* __restrict__ part,
                             u8* __restrict__ Xn, u8* __restrict__ Sn) {
    __shared__ float tile[64][65];
    __shared__ float invsh[64];
    const float* src = blockIdx.z ? s : x;
    u8* dst = blockIdx.z ? Sn : Xn;
    int c0 = blockIdx.y * 64;
    int j0 = blockIdx.x * 64;
    int t = threadIdx.x;
    if (t < 64) {
        const float* pp = part + (size_t)blockIdx.z * 3 * P_DIM + j0 + t;
        float ss = pp[0] + pp[P_DIM] + pp[2 * P_DIM];
        invsh[t] = QSCALE / (sqrtf(ss) + EPSF);
    }
    #pragma unroll
    for (int it = 0; it < 16; ++it) {
        int idx = it * 256 + t;
        int cr = idx >> 6, jc = idx & 63;
        tile[cr][jc] = src[(c0 + cr) * P_DIM + j0 + jc];
    }
    __syncthreads();
    const int kt = c0 >> 7;
    const int ks = (c0 >> 6) & 1;
    #pragma unroll
    for (int it = 0; it < 2; ++it) {
        int item = it * 256 + t;
        int jr = item >> 3;
        int oct = item & 7;
        float iv = invsh[jr];
        unsigned long long pk = 0;
        #pragma unroll
        for (int o = 0; o < 8; ++o) {
            float v = tile[oct * 8 + o][jr] * iv;
            v = fminf(fmaxf(v, -127.0f), 127.0f);
            int q = (int)rintf(v);
            pk |= ((unsigned long long)(unsigned)(q & 0xFF)) << (8 * o);
        }
        size_t addr;
        if (blockIdx.z) {
            addr = (size_t)(j0 + jr) * C_DIM + c0 + oct * 8;
        } else {
            const int g = (j0 + jr) >> 4;
            const int lane = ((oct >> 1) << 4) + (jr & 15);
            addr = ((((size_t)kt * 1024 + g) * 2 + ks) << 10) + lane * 16 + ((oct & 1) << 3);
        }
        *(unsigned long long*)(dst + addr) = pk;
    }
}

// --- 3. 128x128-tile i8 GEMM: 4 waves (32 rows x 128 cols each), 2 blocks/CU ---
__global__ __launch_bounds__(256, 2) void nnfm_gemm_max(
    const u8* __restrict__ Xn, const u8* __restrict__ Sn,
    float* __restrict__ wmax) {
    __shared__ __align__(16) u8 smB[2][128 * 128];      // 32KB

    const int bid = blockIdx.x;
    const int xcd = bid & 7;
    const int idx = bid >> 3;               // 0..63
    const int iblk = xcd * 16 + (idx & 15); // A residency: 16 iblks/XCD = 1.5MB
    const int split = idx >> 4;             // 0..3
    const int i0 = iblk * 128;
    const int jbase = split * (P_DIM / JSPLIT);

    const int tid = threadIdx.x;
    const int lane = tid & 63;
    const int wid = tid >> 6;               // 0..3
    const int wrow = wid * 32;
    const int lm = lane & 15;

    const int srow = wid * 8 + (lane >> 3);                // staging row base, +c*32
    const int scol = ((lane & 7) ^ (lane >> 3)) * 16;      // swizzled source col (bytes)
    const int kidx0 = (((lane >> 4) + 0) ^ (lane & 7)) * 16;
    const int kidx1 = (((lane >> 4) + 4) ^ (lane & 7)) * 16;

    const u8* Abase = Xn + (size_t)lane * 16;
    const int g0 = iblk * 8 + (wrow >> 4);

#define STAGE_B(jt_t, kk_t, buf_t) { \
    _Pragma("unroll") \
    for (int c = 0; c < 4; ++c) \
      async_copy16(Sn + (size_t)(jbase + (jt_t) * 128 + c * 32 + srow) * C_DIM + (kk_t) * 128 + scol, \
                   &smB[buf_t][(c * 32 + wid * 8) * 128]); }

#define RD_B(BUF, KIDX) { \
    _Pragma("unroll") \
    for (int n = 0; n < 8; ++n) \
      bF[n] = *(const i32x4*)&smB[BUF][(n * 16 + lm) * 128 + (KIDX)]; }

#define MFMA_KS(KK, KS, DOZERO) { \
    if (DOZERO) { \
      _Pragma("unroll") \
      for (int m = 0; m < 2; ++m) \
        _Pragma("unroll") \
        for (int n = 0; n < 8; ++n) \
          acc[m][n] = i32x4{0, 0, 0, 0}; \
    } \
    __builtin_amdgcn_s_setprio(1); \
    _Pragma("unroll") \
    for (int m = 0; m < 2; ++m) \
      _Pragma("unroll") \
      for (int n = 0; n < 8; ++n) \
        acc[m][n] = __builtin_amdgcn_mfma_i32_16x16x64_i8(aR[KK][m][KS], bF[n], acc[m][n], 0, 0, 0); \
    __builtin_amdgcn_s_setprio(0); }

    i32x4 acc[2][8];
    i32x4 aR[KT][2][2];                    // 96 VGPR, static-indexed
    i32x4 bF[8];
    int rmax[2][4];
    #pragma unroll
    for (int m = 0; m < 2; ++m)
        #pragma unroll
        for (int r = 0; r < 4; ++r) rmax[m][r] = (int)0x80000000;

    // prologue: B(0)->buf0, A panel (24 loads), B(1)->buf1 last;
    // vmcnt(4) drains B(0)+A, keeps B(1) in flight.
    STAGE_B(0, 0, 0);
    #pragma unroll
    for (int kk = 0; kk < KT; ++kk)
        #pragma unroll
        for (int m = 0; m < 2; ++m)
            #pragma unroll
            for (int ks = 0; ks < 2; ++ks)
                aR[kk][m][ks] = *(const i32x4*)(Abase +
                    ((((size_t)kk * 1024 + g0 + m) * 2 + ks) << 10));
    STAGE_B(0, 1, 1);
    asm volatile("s_waitcnt vmcnt(4)" ::: "memory");
    BARRIER();

    for (int jt = 0; jt < NJT; ++jt) {
        #pragma unroll
        for (int kk = 0; kk < KT; ++kk) {
            const int buf = kk & 1;
            int kk2 = kk + 2, jt2 = jt;
            if (kk2 >= KT) { kk2 -= KT; jt2 = (jt + 1) & (NJT - 1); }
            const bool z = (kk == 0), rx = (kk == KT - 1);

            RD_B(buf, kidx0)
            MFMA_KS(kk, 0, z)
            RD_B(buf, kidx1)
            STAGE_B(jt2, kk2, buf)           // after all reads of this slot
            MFMA_KS(kk, 1, false)
            if (rx) {
                #pragma unroll
                for (int m = 0; m < 2; ++m)
                    #pragma unroll
                    for (int r = 0; r < 4; ++r) {
                        int mx = acc[m][0][r];
                        #pragma unroll
                        for (int n = 1; n < 8; ++n)
                            if (acc[m][n][r] > mx) mx = acc[m][n][r];
                        if (mx > rmax[m][r]) rmax[m][r] = mx;
                    }
            }
            asm volatile("s_waitcnt vmcnt(4) lgkmcnt(0)" ::: "memory");
            BARRIER();
        }
    }

    // epilogue: waves own disjoint rows -> shfl-fold + direct global write
    const float isc = 1.0f / (QSCALE * QSCALE);
    #pragma unroll
    for (int m = 0; m < 2; ++m)
        #pragma unroll
        for (int r = 0; r < 4; ++r) {
            int v = rmax[m][r];
            int o;
            o = __shfl_xor(v, 1); if (o > v) v = o;
            o = __shfl_xor(v, 2); if (o > v) v = o;
            o = __shfl_xor(v, 4); if (o > v) v = o;
            o = __shfl_xor(v, 8); if (o > v) v = o;
            if (lm == 0) {
                const int row = i0 + wrow + m * 16 + (lane >> 4) * 4 + r;
                wmax[(size_t)split * P_DIM + row] = (float)v * isc;
            }
        }
}

// --- 4. loss = mean(1 - max over 4 partials) ---
__global__ void final_reduce(const float* __restrict__ wmax, float* __restrict__ out) {
    __shared__ float red[256];
    int t = threadIdx.x;
    float sum = 0.f;
    for (int i = t; i < P_DIM; i += 256) {
        float m = wmax[i];
        #pragma unroll
        for (int sp = 1; sp < 4; ++sp) m = fmaxf(m, wmax[(size_t)sp * P_DIM + i]);
        sum += 1.0f - m;
    }
    red[t] = sum;
    __syncthreads();
    for (int st = 128; st > 0; st >>= 1) {
        if (t < st) red[t] += red[t + st];
        __syncthreads();
    }
    if (t == 0) out[0] = red[0] * (1.0f / (float)P_DIM);
}

extern "C" void kernel_launch(void* const* d_in, const int* in_sizes, int n_in,
                              void* d_out, int out_size, void* d_ws, size_t ws_size,
                              hipStream_t stream) {
    const float* x = (const float*)d_in[0];
    const float* s = (const float*)d_in[1];
    float* out = (float*)d_out;
    char* ws = (char*)d_ws;

    u8* Xn = (u8*)(ws + OFF_XN);
    u8* Sn = (u8*)(ws + OFF_SN);
    float* part = (float*)(ws + OFF_PART);
    float* wmax = (float*)(ws + OFF_MAX);

    norm1_kernel<<<dim3(64, 2, 3), 256, 0, stream>>>(x, s, part);
    tnorm_kernel<<<dim3(256, 12, 2), 256, 0, stream>>>(x, s, part, Xn, Sn);
    nnfm_gemm_max<<<dim3((P_DIM / 128) * JSPLIT), 256, 0, stream>>>(Xn, Sn, wmax);
    final_reduce<<<1, 256, 0, stream>>>(wmax, out);
}

// Round 18
// 209.710 us; speedup vs baseline: 2.0479x; 1.0035x over previous
//
#include <hip/hip_runtime.h>
#include <math.h>

// NNFM loss on MI355X.
// loss = mean_i (1 - max_j (xhat_i . shat_j)),  xhat/shat = column-normalized feats.
// R2: XOR-swizzle. R7: i8 16x16x64. R8: 2 blocks/CU. R10: XCD residency map.
// R14: A register-resident -> GEMM 167us. R17: 256-thread blocks (4 waves,
//      32 rows x 128 cols each) -> GEMM 160us, MfmaUtil 61%. GEMM is ~33% above
//      its per-CU LDS-BW floor; schedule tweaks have been null all session.
// R18: prep vectorization only (G13): float4 loads in norm1 + tnorm. GEMM untouched.

#define C_DIM 768
#define P_DIM 16384
#define KT 6            // K-tiles (BK=128) : 768/128
#define NJT 32          // j-tiles per block: 4096/128
#define JSPLIT 4
#define EPSF 1e-8f
#define QSCALE 256.0f

typedef unsigned char u8;
typedef int i32x4 __attribute__((ext_vector_type(4)));

// workspace layout (bytes); high-water 50855936 < proven 50987008
#define OFF_XN   0
#define OFF_SN   25165824UL
#define OFF_PART 50462720UL                 // 2*3*16384*4 = 393216 (norm phase)
#define OFF_MAX  50462720UL                 // 4*16384*4 = 262144 (GEMM phase, aliased)

__device__ __forceinline__ void async_copy16(const void* gsrc, void* ldst) {
    __builtin_amdgcn_global_load_lds(
        (const __attribute__((address_space(1))) void*)gsrc,
        (__attribute__((address_space(3))) void*)ldst,
        16, 0, 0);
}

#define CFENCE() asm volatile("" ::: "memory")
#define BARRIER() { CFENCE(); __builtin_amdgcn_s_barrier(); CFENCE(); }

// --- 1. column sum-of-squares partials over c-chunks of 256; float4 columns ---
__global__ void norm1_kernel(const float* __restrict__ x, const float* __restrict__ s,
                             float* __restrict__ part) {
    const float4* src = (const float4*)(blockIdx.y == 0 ? x : s);
    int j4 = blockIdx.x * 256 + threadIdx.x;       // 0..4095 (quad-columns)
    int c0 = blockIdx.z * 256;
    float sx = 0.f, sy = 0.f, sz = 0.f, sw = 0.f;
    for (int c = c0; c < c0 + 256; ++c) {
        float4 v = src[(size_t)c * (P_DIM / 4) + j4];
        sx += v.x * v.x; sy += v.y * v.y; sz += v.z * v.z; sw += v.w * v.w;
    }
    float4* dst = (float4*)(part + ((size_t)blockIdx.y * 3 + blockIdx.z) * P_DIM);
    dst[j4] = float4{sx, sy, sz, sw};
}

// --- 2. transpose, normalize*256 (inv inline from partials), round to int8 ---
// float4 global loads; LDS tile stores scalar (keeps 65-pad conflict-free reads).
// Sn (z=1): row-major [p][c]. Xn (z=0): fragment-linear (verified R11-R17):
//   byte addr = (((kt*1024 + g)*2 + ks)<<10) + lane*16 + (kb&15).
__global__ void tnorm_kernel(const float* __restrict__ x, const float* __restrict__ s,
                             const float* __restrict__ part,
                             u8* __restrict__ Xn, u8* __restrict__ Sn) {
    __shared__ float tile[64][65];
    __shared__ float invsh[64];
    const float* src = blockIdx.z ? s : x;
    u8* dst = blockIdx.z ? Sn : Xn;
    int c0 = blockIdx.y * 64;
    int j0 = blockIdx.x * 64;
    int t = threadIdx.x;
    if (t < 64) {
        const float* pp = part + (size_t)blockIdx.z * 3 * P_DIM + j0 + t;
        float ss = pp[0] + pp[P_DIM] + pp[2 * P_DIM];
        invsh[t] = QSCALE / (sqrtf(ss) + EPSF);
    }
    #pragma unroll
    for (int it = 0; it < 4; ++it) {
        int idx = it * 256 + t;                    // 0..1023 quad-slots
        int cr = idx >> 4, jc = (idx & 15) * 4;
        float4 v = *(const float4*)&src[(size_t)(c0 + cr) * P_DIM + j0 + jc];
        tile[cr][jc + 0] = v.x;
        tile[cr][jc + 1] = v.y;
        tile[cr][jc + 2] = v.z;
        tile[cr][jc + 3] = v.w;
    }
    __syncthreads();
    const int kt = c0 >> 7;
    const int ks = (c0 >> 6) & 1;
    #pragma unroll
    for (int it = 0; it < 2; ++it) {
        int item = it * 256 + t;
        int jr = item >> 3;
        int oct = item & 7;
        float iv = invsh[jr];
        unsigned long long pk = 0;
        #pragma unroll
        for (int o = 0; o < 8; ++o) {
            float v = tile[oct * 8 + o][jr] * iv;
            v = fminf(fmaxf(v, -127.0f), 127.0f);
            int q = (int)rintf(v);
            pk |= ((unsigned long long)(unsigned)(q & 0xFF)) << (8 * o);
        }
        size_t addr;
        if (blockIdx.z) {
            addr = (size_t)(j0 + jr) * C_DIM + c0 + oct * 8;
        } else {
            const int g = (j0 + jr) >> 4;
            const int lane = ((oct >> 1) << 4) + (jr & 15);
            addr = ((((size_t)kt * 1024 + g) * 2 + ks) << 10) + lane * 16 + ((oct & 1) << 3);
        }
        *(unsigned long long*)(dst + addr) = pk;
    }
}

// --- 3. 128x128-tile i8 GEMM: 4 waves (32 rows x 128 cols each), 2 blocks/CU ---
// (byte-identical to R17)
__global__ __launch_bounds__(256, 2) void nnfm_gemm_max(
    const u8* __restrict__ Xn, const u8* __restrict__ Sn,
    float* __restrict__ wmax) {
    __shared__ __align__(16) u8 smB[2][128 * 128];      // 32KB

    const int bid = blockIdx.x;
    const int xcd = bid & 7;
    const int idx = bid >> 3;               // 0..63
    const int iblk = xcd * 16 + (idx & 15); // A residency: 16 iblks/XCD = 1.5MB
    const int split = idx >> 4;             // 0..3
    const int i0 = iblk * 128;
    const int jbase = split * (P_DIM / JSPLIT);

    const int tid = threadIdx.x;
    const int lane = tid & 63;
    const int wid = tid >> 6;               // 0..3
    const int wrow = wid * 32;
    const int lm = lane & 15;

    const int srow = wid * 8 + (lane >> 3);                // staging row base, +c*32
    const int scol = ((lane & 7) ^ (lane >> 3)) * 16;      // swizzled source col (bytes)
    const int kidx0 = (((lane >> 4) + 0) ^ (lane & 7)) * 16;
    const int kidx1 = (((lane >> 4) + 4) ^ (lane & 7)) * 16;

    const u8* Abase = Xn + (size_t)lane * 16;
    const int g0 = iblk * 8 + (wrow >> 4);

#define STAGE_B(jt_t, kk_t, buf_t) { \
    _Pragma("unroll") \
    for (int c = 0; c < 4; ++c) \
      async_copy16(Sn + (size_t)(jbase + (jt_t) * 128 + c * 32 + srow) * C_DIM + (kk_t) * 128 + scol, \
                   &smB[buf_t][(c * 32 + wid * 8) * 128]); }

#define RD_B(BUF, KIDX) { \
    _Pragma("unroll") \
    for (int n = 0; n < 8; ++n) \
      bF[n] = *(const i32x4*)&smB[BUF][(n * 16 + lm) * 128 + (KIDX)]; }

#define MFMA_KS(KK, KS, DOZERO) { \
    if (DOZERO) { \
      _Pragma("unroll") \
      for (int m = 0; m < 2; ++m) \
        _Pragma("unroll") \
        for (int n = 0; n < 8; ++n) \
          acc[m][n] = i32x4{0, 0, 0, 0}; \
    } \
    __builtin_amdgcn_s_setprio(1); \
    _Pragma("unroll") \
    for (int m = 0; m < 2; ++m) \
      _Pragma("unroll") \
      for (int n = 0; n < 8; ++n) \
        acc[m][n] = __builtin_amdgcn_mfma_i32_16x16x64_i8(aR[KK][m][KS], bF[n], acc[m][n], 0, 0, 0); \
    __builtin_amdgcn_s_setprio(0); }

    i32x4 acc[2][8];
    i32x4 aR[KT][2][2];                    // 96 VGPR, static-indexed
    i32x4 bF[8];
    int rmax[2][4];
    #pragma unroll
    for (int m = 0; m < 2; ++m)
        #pragma unroll
        for (int r = 0; r < 4; ++r) rmax[m][r] = (int)0x80000000;

    // prologue: B(0)->buf0, A panel (24 loads), B(1)->buf1 last;
    // vmcnt(4) drains B(0)+A, keeps B(1) in flight.
    STAGE_B(0, 0, 0);
    #pragma unroll
    for (int kk = 0; kk < KT; ++kk)
        #pragma unroll
        for (int m = 0; m < 2; ++m)
            #pragma unroll
            for (int ks = 0; ks < 2; ++ks)
                aR[kk][m][ks] = *(const i32x4*)(Abase +
                    ((((size_t)kk * 1024 + g0 + m) * 2 + ks) << 10));
    STAGE_B(0, 1, 1);
    asm volatile("s_waitcnt vmcnt(4)" ::: "memory");
    BARRIER();

    for (int jt = 0; jt < NJT; ++jt) {
        #pragma unroll
        for (int kk = 0; kk < KT; ++kk) {
            const int buf = kk & 1;
            int kk2 = kk + 2, jt2 = jt;
            if (kk2 >= KT) { kk2 -= KT; jt2 = (jt + 1) & (NJT - 1); }
            const bool z = (kk == 0), rx = (kk == KT - 1);

            RD_B(buf, kidx0)
            MFMA_KS(kk, 0, z)
            RD_B(buf, kidx1)
            STAGE_B(jt2, kk2, buf)           // after all reads of this slot
            MFMA_KS(kk, 1, false)
            if (rx) {
                #pragma unroll
                for (int m = 0; m < 2; ++m)
                    #pragma unroll
                    for (int r = 0; r < 4; ++r) {
                        int mx = acc[m][0][r];
                        #pragma unroll
                        for (int n = 1; n < 8; ++n)
                            if (acc[m][n][r] > mx) mx = acc[m][n][r];
                        if (mx > rmax[m][r]) rmax[m][r] = mx;
                    }
            }
            asm volatile("s_waitcnt vmcnt(4) lgkmcnt(0)" ::: "memory");
            BARRIER();
        }
    }

    // epilogue: waves own disjoint rows -> shfl-fold + direct global write
    const float isc = 1.0f / (QSCALE * QSCALE);
    #pragma unroll
    for (int m = 0; m < 2; ++m)
        #pragma unroll
        for (int r = 0; r < 4; ++r) {
            int v = rmax[m][r];
            int o;
            o = __shfl_xor(v, 1); if (o > v) v = o;
            o = __shfl_xor(v, 2); if (o > v) v = o;
            o = __shfl_xor(v, 4); if (o > v) v = o;
            o = __shfl_xor(v, 8); if (o > v) v = o;
            if (lm == 0) {
                const int row = i0 + wrow + m * 16 + (lane >> 4) * 4 + r;
                wmax[(size_t)split * P_DIM + row] = (float)v * isc;
            }
        }
}

// --- 4. loss = mean(1 - max over 4 partials) ---
__global__ void final_reduce(const float* __restrict__ wmax, float* __restrict__ out) {
    __shared__ float red[256];
    int t = threadIdx.x;
    float sum = 0.f;
    for (int i = t; i < P_DIM; i += 256) {
        float m = wmax[i];
        #pragma unroll
        for (int sp = 1; sp < 4; ++sp) m = fmaxf(m, wmax[(size_t)sp * P_DIM + i]);
        sum += 1.0f - m;
    }
    red[t] = sum;
    __syncthreads();
    for (int st = 128; st > 0; st >>= 1) {
        if (t < st) red[t] += red[t + st];
        __syncthreads();
    }
    if (t == 0) out[0] = red[0] * (1.0f / (float)P_DIM);
}

extern "C" void kernel_launch(void* const* d_in, const int* in_sizes, int n_in,
                              void* d_out, int out_size, void* d_ws, size_t ws_size,
                              hipStream_t stream) {
    const float* x = (const float*)d_in[0];
    const float* s = (const float*)d_in[1];
    float* out = (float*)d_out;
    char* ws = (char*)d_ws;

    u8* Xn = (u8*)(ws + OFF_XN);
    u8* Sn = (u8*)(ws + OFF_SN);
    float* part = (float*)(ws + OFF_PART);
    float* wmax = (float*)(ws + OFF_MAX);

    norm1_kernel<<<dim3(16, 2, 3), 256, 0, stream>>>(x, s, part);
    tnorm_kernel<<<dim3(256, 12, 2), 256, 0, stream>>>(x, s, part, Xn, Sn);
    nnfm_gemm_max<<<dim3((P_DIM / 128) * JSPLIT), 256, 0, stream>>>(Xn, Sn, wmax);
    final_reduce<<<1, 256, 0, stream>>>(wmax, out);
}